// Round 5
// baseline (284.080 us; speedup 1.0000x reference)
//
#include <hip/hip_runtime.h>

// Problem constants (from reference)
#define DIM_IN   2048
#define FEAT     128
#define KP1      16385      // NCE_N + 1
#define NDATA    100000
#define BATCH    64
#define RT       128        // rows per gemm tile
#define NTILES   ((NDATA + RT - 1) / RT)   // 782
#define SAS      68         // sA row stride (floats); 68 % 32 == 4 -> conflict-free
#define GCH      8          // k-chunks per (side,b) in gather kernel

constexpr float NCE_T_INV = 1.0f / 0.07f;
constexpr float M_CONST   = 16384.0f / 100000.0f;   // NCE_N / N_DATA
constexpr float EPS_C     = 1e-7f;

// ---------------------------------------------------------------------------
// Kernel 1: h = l2norm(feat @ w.T + b). Per-wave coalesced row dots.
// ---------------------------------------------------------------------------
__global__ void __launch_bounds__(256) embed_kernel(
    const float* __restrict__ feat_s, const float* __restrict__ feat_t,
    const float* __restrict__ w_s, const float* __restrict__ b_s,
    const float* __restrict__ w_t, const float* __restrict__ b_t,
    float* __restrict__ v_out)
{
    const int blk  = blockIdx.x;      // side*64 + b
    const int side = blk >> 6;
    const int b    = blk & 63;
    const float* feat = (side == 0 ? feat_s : feat_t) + (size_t)b * DIM_IN;
    const float* w    = (side == 0 ? w_s : w_t);
    const float* bias = (side == 0 ? b_s : b_t);

    __shared__ float sfeat[DIM_IN];
    __shared__ float pre[FEAT];
    __shared__ float wsum[2];

    const int t = threadIdx.x;
    {   // coalesced float4 stage of the feat row (8 KB)
        const float4* f4 = (const float4*)feat;
        float4* s4 = (float4*)sfeat;
        for (int j = t; j < DIM_IN / 4; j += 256) s4[j] = f4[j];
    }
    __syncthreads();

    const int wv = t >> 6, ln = t & 63;
    const float4* w4  = (const float4*)w;
    const float4* sf4 = (const float4*)sfeat;
    for (int d = wv; d < FEAT; d += 4) {
        float s = 0.f;
#pragma unroll
        for (int seg = 0; seg < 8; ++seg) {      // 512 float4 per row / 64 lanes
            float4 a = w4[d * (DIM_IN / 4) + seg * 64 + ln];
            float4 f = sf4[seg * 64 + ln];
            s += a.x * f.x + a.y * f.y + a.z * f.z + a.w * f.w;
        }
#pragma unroll
        for (int o = 32; o > 0; o >>= 1) s += __shfl_xor(s, o, 64);
        if (ln == 0) pre[d] = s;
    }
    __syncthreads();

    if (t < 128) {
        float p = pre[t] + bias[t];
        pre[t] = p;
        float sq = p * p;
#pragma unroll
        for (int o = 32; o > 0; o >>= 1) sq += __shfl_xor(sq, o, 64);
        if ((t & 63) == 0) wsum[t >> 6] = sq;
    }
    __syncthreads();
    if (t < 128) {
        float inv_norm = 1.0f / sqrtf(wsum[0] + wsum[1]);
        v_out[(size_t)blk * FEAT + t] = pre[t] * inv_norm;
    }
}

// ---------------------------------------------------------------------------
// Kernel 2: dense skinny GEMM + exp. E[sb][n] = exp(dot(bank[n], v[sb])/T).
// R5: 128-row x 64-anchor tile, K in two 64-wide passes.
//  - sA padded stride 68 (==4 mod 32). Thread rows INTERLEAVED (rg+32j):
//    a wave's 8 rg-broadcast b128 A-reads start at banks 4*((rg+c)%8)*...
//    -> 8 distinct bank-quads covering all 32 banks: conflict-free.
//  - LDS 50.8 KB -> 3 blocks/CU (cross-block overlap of stage/compute).
//  - Pass-1 A/B prefetched into VGPRs during pass-0 compute: the global
//    latency hides under 2048 FMAs; after the barrier only ds_write remains.
// ---------------------------------------------------------------------------
__global__ void __launch_bounds__(256, 3) gemm_exp_kernel(
    const float* __restrict__ mem_v1, const float* __restrict__ mem_v2,
    const float* __restrict__ v_in, float* __restrict__ E)
{
    __shared__ __align__(16) float sA[RT * SAS];  // 34.8 KB
    __shared__ __align__(16) float sB[64 * 64];   // [k][b] 16 KB

    const int bx   = blockIdx.x;
    const int side = bx & 1;
    const int tile = bx >> 1;
    const int n0   = tile * RT;
    const float* bank = (side == 0 ? mem_v2 : mem_v1);
    const float* vb   = v_in + (size_t)side * 64 * FEAT;
    const int t  = threadIdx.x;
    const int ag = t & 7;             // anchors ag*8..+7
    const int rg = t >> 3;            // rows n0 + rg + 32j, j=0..3

    float acc[4][8];
#pragma unroll
    for (int i = 0; i < 4; ++i)
#pragma unroll
        for (int j = 0; j < 8; ++j) acc[i][j] = 0.f;

    // ---- stage pass 0 (through regs; nothing to hide under yet) ----
    float4 pfA[8], pfB[4];
#pragma unroll
    for (int it = 0; it < 8; ++it) {
        const int i = t + it * 256;
        const int r = i >> 4, f = i & 15;
        int row = n0 + r; if (row > NDATA - 1) row = NDATA - 1;
        pfA[it] = *(const float4*)(bank + (size_t)row * FEAT + f * 4);
    }
#pragma unroll
    for (int it = 0; it < 4; ++it) {
        const int i = t + it * 256;
        const int b2 = i & 63, f = i >> 6;
        pfB[it] = *(const float4*)(vb + (size_t)b2 * FEAT + f * 4);
    }
#pragma unroll
    for (int it = 0; it < 8; ++it) {
        const int i = t + it * 256;
        const int r = i >> 4, f = i & 15;
        *(float4*)&sA[r * SAS + f * 4] = pfA[it];
    }
#pragma unroll
    for (int it = 0; it < 4; ++it) {
        const int i = t + it * 256;
        const int b2 = i & 63, f = i >> 6;
        sB[(f * 4 + 0) * 64 + b2] = pfB[it].x;
        sB[(f * 4 + 1) * 64 + b2] = pfB[it].y;
        sB[(f * 4 + 2) * 64 + b2] = pfB[it].z;
        sB[(f * 4 + 3) * 64 + b2] = pfB[it].w;
    }
    __syncthreads();

    // ---- prefetch pass 1 into regs (latency hides under compute 0) ----
#pragma unroll
    for (int it = 0; it < 8; ++it) {
        const int i = t + it * 256;
        const int r = i >> 4, f = i & 15;
        int row = n0 + r; if (row > NDATA - 1) row = NDATA - 1;
        pfA[it] = *(const float4*)(bank + (size_t)row * FEAT + 64 + f * 4);
    }
#pragma unroll
    for (int it = 0; it < 4; ++it) {
        const int i = t + it * 256;
        const int b2 = i & 63, f = i >> 6;
        pfB[it] = *(const float4*)(vb + (size_t)b2 * FEAT + 64 + f * 4);
    }

    // ---- compute pass 0 ----
#pragma unroll 1
    for (int c = 0; c < 16; ++c) {
        float4 af[4], bf[8];
#pragma unroll
        for (int j = 0; j < 4; ++j)
            af[j] = *(const float4*)&sA[(rg + 32 * j) * SAS + c * 4];
#pragma unroll
        for (int kk = 0; kk < 4; ++kk) {
            bf[kk * 2 + 0] = *(const float4*)&sB[(c * 4 + kk) * 64 + ag * 8];
            bf[kk * 2 + 1] = *(const float4*)&sB[(c * 4 + kk) * 64 + ag * 8 + 4];
        }
#pragma unroll
        for (int kk = 0; kk < 4; ++kk)
#pragma unroll
            for (int j = 0; j < 4; ++j) {
                const float a = (kk == 0) ? af[j].x : (kk == 1) ? af[j].y
                              : (kk == 2) ? af[j].z : af[j].w;
                acc[j][0] += a * bf[kk * 2].x;  acc[j][1] += a * bf[kk * 2].y;
                acc[j][2] += a * bf[kk * 2].z;  acc[j][3] += a * bf[kk * 2].w;
                acc[j][4] += a * bf[kk * 2 + 1].x;  acc[j][5] += a * bf[kk * 2 + 1].y;
                acc[j][6] += a * bf[kk * 2 + 1].z;  acc[j][7] += a * bf[kk * 2 + 1].w;
            }
    }
    __syncthreads();

    // ---- write pass-1 tiles (data already in regs) ----
#pragma unroll
    for (int it = 0; it < 8; ++it) {
        const int i = t + it * 256;
        const int r = i >> 4, f = i & 15;
        *(float4*)&sA[r * SAS + f * 4] = pfA[it];
    }
#pragma unroll
    for (int it = 0; it < 4; ++it) {
        const int i = t + it * 256;
        const int b2 = i & 63, f = i >> 6;
        sB[(f * 4 + 0) * 64 + b2] = pfB[it].x;
        sB[(f * 4 + 1) * 64 + b2] = pfB[it].y;
        sB[(f * 4 + 2) * 64 + b2] = pfB[it].z;
        sB[(f * 4 + 3) * 64 + b2] = pfB[it].w;
    }
    __syncthreads();

    // ---- compute pass 1 ----
#pragma unroll 1
    for (int c = 0; c < 16; ++c) {
        float4 af[4], bf[8];
#pragma unroll
        for (int j = 0; j < 4; ++j)
            af[j] = *(const float4*)&sA[(rg + 32 * j) * SAS + c * 4];
#pragma unroll
        for (int kk = 0; kk < 4; ++kk) {
            bf[kk * 2 + 0] = *(const float4*)&sB[(c * 4 + kk) * 64 + ag * 8];
            bf[kk * 2 + 1] = *(const float4*)&sB[(c * 4 + kk) * 64 + ag * 8 + 4];
        }
#pragma unroll
        for (int kk = 0; kk < 4; ++kk)
#pragma unroll
            for (int j = 0; j < 4; ++j) {
                const float a = (kk == 0) ? af[j].x : (kk == 1) ? af[j].y
                              : (kk == 2) ? af[j].z : af[j].w;
                acc[j][0] += a * bf[kk * 2].x;  acc[j][1] += a * bf[kk * 2].y;
                acc[j][2] += a * bf[kk * 2].z;  acc[j][3] += a * bf[kk * 2].w;
                acc[j][4] += a * bf[kk * 2 + 1].x;  acc[j][5] += a * bf[kk * 2 + 1].y;
                acc[j][6] += a * bf[kk * 2 + 1].z;  acc[j][7] += a * bf[kk * 2 + 1].w;
            }
    }

    // ---- epilogue: exp + store E[sb][n] ----
    // lanes sharing (ag): rg consecutive -> 8 consecutive n per 32 B segment.
#pragma unroll
    for (int j = 0; j < 4; ++j) {
        const int row = n0 + rg + 32 * j;
        if (row < NDATA) {
#pragma unroll
            for (int jj = 0; jj < 8; ++jj)
                E[(size_t)(side * 64 + ag * 8 + jj) * NDATA + row] =
                    __expf(acc[j][jj] * NCE_T_INV);
        }
    }
}

// ---------------------------------------------------------------------------
// Kernel 3: gather ex = E[sb][idx[b,k]], store compact, accumulate Z[sb].
// ---------------------------------------------------------------------------
__global__ void __launch_bounds__(256) gather_z_kernel(
    const int* __restrict__ sample_idx, const float* __restrict__ E,
    float* __restrict__ ex_out, float* __restrict__ z_out)
{
    const int blk   = blockIdx.x;
    const int chunk = blk >> 7;          // 0..GCH-1
    const int sb    = blk & 127;         // side*64 + b
    const int b     = sb & 63;
    const float* Eb = E + (size_t)sb * NDATA;

    float zp = 0.f;
    for (int k = chunk * 256 + threadIdx.x; k < KP1; k += GCH * 256) {
        const int idx = sample_idx[(size_t)b * KP1 + k];
        const float e = Eb[idx];
        ex_out[(size_t)sb * KP1 + k] = e;
        zp += e;
    }
#pragma unroll
    for (int o = 32; o > 0; o >>= 1) zp += __shfl_xor(zp, o, 64);
    __shared__ float zw[4];
    if ((threadIdx.x & 63) == 0) zw[threadIdx.x >> 6] = zp;
    __syncthreads();
    if (threadIdx.x == 0) atomicAdd(&z_out[sb], zw[0] + zw[1] + zw[2] + zw[3]);
}

// ---------------------------------------------------------------------------
// Kernel 4: loss. 256 blocks (2 chunks x 128 sb); Z summed in-kernel.
// ---------------------------------------------------------------------------
__global__ void __launch_bounds__(256) loss_kernel(
    const float* __restrict__ ex_in, const float* __restrict__ z_in,
    float* __restrict__ out)
{
    const int blk   = blockIdx.x;
    const int chunk = blk >> 7;          // 0..1
    const int sb    = blk & 127;
    const int side  = sb >> 6;

    __shared__ float zsh;
    if (threadIdx.x < 64) {
        float zv = z_in[side * 64 + threadIdx.x];
#pragma unroll
        for (int o = 32; o > 0; o >>= 1) zv += __shfl_xor(zv, o, 64);
        if (threadIdx.x == 0) zsh = zv;
    }
    __syncthreads();

    const float z  = zsh * ((float)NDATA / (64.0f * (float)KP1));
    const float rz = 1.0f / z;
    const float* ex = ex_in + (size_t)sb * KP1;

    float part = 0.f;
    for (int k = chunk * 256 + threadIdx.x; k < KP1; k += 512) {
        const float x = ex[k] * rz;
        if (k == 0) part += __logf(x / (x + M_CONST + EPS_C));
        else        part += __logf(M_CONST / (x + M_CONST + EPS_C));
    }
#pragma unroll
    for (int o = 32; o > 0; o >>= 1) part += __shfl_xor(part, o, 64);
    __shared__ float pw[4];
    if ((threadIdx.x & 63) == 0) pw[threadIdx.x >> 6] = part;
    __syncthreads();
    if (threadIdx.x == 0)
        atomicAdd(out, -(pw[0] + pw[1] + pw[2] + pw[3]) * (1.0f / 64.0f));
}

// ---------------------------------------------------------------------------
extern "C" void kernel_launch(void* const* d_in, const int* in_sizes, int n_in,
                              void* d_out, int out_size, void* d_ws, size_t ws_size,
                              hipStream_t stream)
{
    const float* feat_s     = (const float*)d_in[0];
    const float* feat_t     = (const float*)d_in[1];
    /* d_in[2] = idx, unused: sample_idx[:,0] already holds it */
    const int*   sample_idx = (const int*)  d_in[3];
    const float* w_s        = (const float*)d_in[4];
    const float* b_s        = (const float*)d_in[5];
    const float* w_t        = (const float*)d_in[6];
    const float* b_t        = (const float*)d_in[7];
    const float* mem_v1     = (const float*)d_in[8];
    const float* mem_v2     = (const float*)d_in[9];
    float* out = (float*)d_out;

    // Workspace layout:
    //   [z: 128 f32 = 512 B]
    //   [v: 2*64*128 f32 = 64 KB]
    //   [ex: 2*64*16385 f32 = 8.39 MB]
    //   [E: 128*100000 f32 = 51.2 MB]  (transposed: E[sb][n])
    char*  ws    = (char*)d_ws;
    float* ws_z  = (float*)ws;
    float* ws_v  = (float*)(ws + 512);
    float* ws_ex = (float*)(ws + 512 + 2 * BATCH * FEAT * sizeof(float));
    float* ws_E  = (float*)(ws + 512 + 2 * BATCH * FEAT * sizeof(float)
                               + (size_t)2 * BATCH * KP1 * sizeof(float));

    hipMemsetAsync(ws_z, 0, 128 * sizeof(float), stream);
    hipMemsetAsync(out, 0, sizeof(float), stream);

    embed_kernel<<<2 * BATCH, 256, 0, stream>>>(feat_s, feat_t, w_s, b_s, w_t, b_t, ws_v);
    gemm_exp_kernel<<<2 * NTILES, 256, 0, stream>>>(mem_v1, mem_v2, ws_v, ws_E);
    gather_z_kernel<<<2 * BATCH * GCH, 256, 0, stream>>>(sample_idx, ws_E, ws_ex, ws_z);
    loss_kernel<<<2 * BATCH * 2, 256, 0, stream>>>(ws_ex, ws_z, out);
}